// Round 3
// baseline (4856.578 us; speedup 1.0000x reference)
//
#include <hip/hip_runtime.h>
#include <hip/hip_bf16.h>
#include <math.h>

typedef __hip_bfloat16 bf16;

#define NODES 10000
#define NEDGE 240000
#define NBOND 240000
#define HID   256
#define HEADS 16
#define HD    16
#define NG    20
#define ETD   4
#define EFD   84   // NG*ETD + ETD

__device__ inline float toF(float x) { return x; }
__device__ inline float toF(bf16 x)  { return __bfloat162float(x); }
__device__ inline void storeC(float* p, float v) { *p = v; }
__device__ inline void storeC(bf16*  p, float v) { *p = __float2bfloat16(v); }

enum { EPI_NONE=0, EPI_BIAS=1, EPI_BIAS_SILU=2, EPI_TANH=3, EPI_BIAS_ADD=4 };

// ---------------- generic tiled GEMM: C[M,Nc] = epi(A[M,K] @ B[K,Nc]) ----------------
// A: row-major fp32, B: row-major fp32 weights, acc fp32.
template<typename TA, typename TC, int EPI>
__global__ __launch_bounds__(256)
void gemm_kernel(const TA* __restrict__ A, const float* __restrict__ B,
                 const float* __restrict__ bias, const float* __restrict__ addsrc,
                 TC* __restrict__ C, int M, int Nc, int K)
{
    __shared__ float As[16][64];
    __shared__ float Bs[16][64];
    const int tid = threadIdx.x;
    const int tx = tid & 15, ty = tid >> 4;
    const int row0 = blockIdx.x * 64, col0 = blockIdx.y * 64;

    float acc[4][4] = {};
    for (int k0 = 0; k0 < K; k0 += 16) {
        #pragma unroll
        for (int l = 0; l < 4; ++l) {            // A tile 64x16
            int idx = tid + l * 256;
            int r = idx >> 4, kk = idx & 15;
            int gr = row0 + r, gk = k0 + kk;
            As[kk][r] = (gr < M && gk < K) ? toF(A[(size_t)gr * K + gk]) : 0.f;
        }
        #pragma unroll
        for (int l = 0; l < 4; ++l) {            // B tile 16x64
            int idx = tid + l * 256;
            int kk = idx >> 6, c = idx & 63;
            int gk = k0 + kk;
            Bs[kk][c] = (gk < K) ? B[(size_t)gk * Nc + col0 + c] : 0.f;
        }
        __syncthreads();
        #pragma unroll
        for (int kk = 0; kk < 16; ++kk) {
            float a[4], b[4];
            #pragma unroll
            for (int i = 0; i < 4; ++i) a[i] = As[kk][ty * 4 + i];
            #pragma unroll
            for (int j = 0; j < 4; ++j) b[j] = Bs[kk][tx * 4 + j];
            #pragma unroll
            for (int i = 0; i < 4; ++i)
                #pragma unroll
                for (int j = 0; j < 4; ++j) acc[i][j] += a[i] * b[j];
        }
        __syncthreads();
    }
    #pragma unroll
    for (int i = 0; i < 4; ++i) {
        int gr = row0 + ty * 4 + i;
        if (gr >= M) continue;
        #pragma unroll
        for (int j = 0; j < 4; ++j) {
            int gc = col0 + tx * 4 + j;
            float v = acc[i][j];
            if (EPI == EPI_BIAS || EPI == EPI_BIAS_SILU || EPI == EPI_BIAS_ADD)
                v += bias[gc];
            if (EPI == EPI_BIAS_SILU) v = v / (1.f + expf(-v));
            if (EPI == EPI_TANH)      v = tanhf(v);
            if (EPI == EPI_BIAS_ADD)  v += addsrc[(size_t)gr * Nc + gc];
            storeC(C + (size_t)gr * Nc + gc, v);
        }
    }
}

// --------- fused edge-feature kernel (attn 1): ef = [et⊗gauss(dist), et]; e0/e1 = tanh(ef @ We) ---------
// Weights staged in LDS as bf16 (fp32 pair would exceed 64 KB static LDS).
__global__ __launch_bounds__(128)
void edge_ef_kernel(const float* __restrict__ pos, const float* __restrict__ edge_type,
                    const int* __restrict__ eidx, const float* __restrict__ We0,
                    const float* __restrict__ We1, bf16* __restrict__ e0,
                    bf16* __restrict__ e1)
{
    __shared__ bf16 sW0[EFD * 128];
    __shared__ bf16 sW1[EFD * 128];
    __shared__ float sef[EFD];
    const int tid = threadIdx.x;
    const int half = blockIdx.y;          // channel half: 0 or 1
    for (int idx = tid; idx < EFD * 128; idx += 128) {
        int j = idx >> 7, c = idx & 127;
        sW0[idx] = __float2bfloat16(We0[j * HID + half * 128 + c]);
        sW1[idx] = __float2bfloat16(We1[j * HID + half * 128 + c]);
    }
    __syncthreads();

    for (int e = blockIdx.x; e < NEDGE; e += gridDim.x) {
        int src = eidx[e];
        int dst = eidx[NEDGE + e];
        if (tid < EFD) {
            float dx = pos[dst * 3 + 0] - pos[src * 3 + 0];
            float dy = pos[dst * 3 + 1] - pos[src * 3 + 1];
            float dz = pos[dst * 3 + 2] - pos[src * 3 + 2];
            float dist = sqrtf(dx * dx + dy * dy + dz * dz + 1e-12f);
            if (tid < NG * ETD) {
                int t = tid / NG, g = tid % NG;
                float off = (10.0f / 19.0f) * (float)g;
                float d = dist - off;
                const float coeff = -0.5f * (19.f * 19.f) / (10.f * 10.f);
                sef[tid] = edge_type[e * ETD + t] * expf(coeff * d * d);
            } else {
                sef[tid] = edge_type[e * ETD + (tid - NG * ETD)];
            }
        }
        __syncthreads();
        float a0 = 0.f, a1 = 0.f;
        #pragma unroll 4
        for (int j = 0; j < EFD; ++j) {
            float ef = sef[j];
            a0 += ef * toF(sW0[j * 128 + tid]);
            a1 += ef * toF(sW1[j * 128 + tid]);
        }
        size_t o = (size_t)e * HID + half * 128 + tid;
        e0[o] = __float2bfloat16(tanhf(a0));
        e1[o] = __float2bfloat16(tanhf(a1));
        __syncthreads();
    }
}

// --------- alpha pass: exp(q[dst]·k[src]·e0 / 4), accumulate softmax denominators ---------
// No segment-max: |alpha| small for this data, exp fp32-safe; every denom that is
// read received at least this edge's own contribution -> no 0/0.
__global__ __launch_bounds__(256)
void alpha_kernel(const int* __restrict__ eidx, const float* __restrict__ q,
                  const float* __restrict__ k, const bf16* __restrict__ e0,
                  float* __restrict__ alphaE, float* __restrict__ denom, int Ecnt)
{
    int gid = blockIdx.x * blockDim.x + threadIdx.x;
    if (gid >= Ecnt * HEADS) return;
    int e = gid >> 4, h = gid & 15;
    int src = eidx[e], dst = eidx[Ecnt + e];
    const float* qp = q + (size_t)dst * HID + h * HD;
    const float* kp = k + (size_t)src * HID + h * HD;
    const bf16* ep = e0 + (size_t)e * HID + h * HD;
    float a = 0.f;
    #pragma unroll
    for (int c = 0; c < HD; ++c) a += qp[c] * kp[c] * toF(ep[c]);
    a *= 0.25f;                   // 1/sqrt(16)
    float ex = __expf(a);
    alphaE[gid] = ex;
    atomicAdd(&denom[dst * HEADS + h], ex);
}

// --------- message pass: atomically scatter v[src]*e1*softmax into cat[:, :256] ---------
__global__ __launch_bounds__(256)
void msg_kernel(const int* __restrict__ eidx, const float* __restrict__ v,
                const bf16* __restrict__ e1, const float* __restrict__ alphaE,
                const float* __restrict__ denom, float* __restrict__ cat, int Ecnt)
{
    int gid = blockIdx.x * blockDim.x + threadIdx.x;
    int e = gid >> 8, c = gid & 255;
    if (e >= Ecnt) return;
    int h = c >> 4;
    int src = eidx[e], dst = eidx[Ecnt + e];
    float w = alphaE[e * HEADS + h] / denom[dst * HEADS + h];
    float val = v[(size_t)src * HID + c] * toF(e1[(size_t)e * HID + c]) * w;
    atomicAdd(&cat[(size_t)dst * 512 + c], val);
}

// --------- cat buffer init: left half 0 (accumulator), right half x ---------
__global__ __launch_bounds__(256)
void fill_cat_kernel(const float* __restrict__ x, float* __restrict__ cat)
{
    int gid = blockIdx.x * blockDim.x + threadIdx.x;   // NODES*512
    int n = gid >> 9, j = gid & 511;
    cat[gid] = (j < 256) ? 0.f : x[(size_t)n * HID + (j - 256)];
}

__global__ __launch_bounds__(256)
void zero_kernel(float* __restrict__ p, int n)
{
    int gid = blockIdx.x * blockDim.x + threadIdx.x;
    if (gid < n) p[gid] = 0.f;
}

// --------- row LayerNorm (256 cols), optional +fp32 residual before, optional ReLU after ---------
template<bool RELU, bool ADD>
__global__ __launch_bounds__(256)
void ln_kernel(const float* __restrict__ x, const float* __restrict__ add,
               float* __restrict__ y, float eps)
{
    __shared__ float red[256];
    int row = blockIdx.x, tid = threadIdx.x;
    float v = x[(size_t)row * HID + tid];
    if (ADD) v += add[(size_t)row * HID + tid];
    red[tid] = v; __syncthreads();
    for (int s = 128; s > 0; s >>= 1) { if (tid < s) red[tid] += red[tid + s]; __syncthreads(); }
    float mu = red[0] * (1.f / 256.f);
    __syncthreads();
    float d = v - mu;
    red[tid] = d * d; __syncthreads();
    for (int s = 128; s > 0; s >>= 1) { if (tid < s) red[tid] += red[tid + s]; __syncthreads(); }
    float var = red[0] * (1.f / 256.f);
    float out = d * rsqrtf(var + eps);
    if (RELU) out = fmaxf(out, 0.f);
    y[(size_t)row * HID + tid] = out;
}

extern "C" void kernel_launch(void* const* d_in, const int* in_sizes, int n_in,
                              void* d_out, int out_size, void* d_ws, size_t ws_size,
                              hipStream_t stream)
{
    const float* h         = (const float*)d_in[0];
    const float* h_bond    = (const float*)d_in[1];
    const float* pos       = (const float*)d_in[2];
    const float* edge_type = (const float*)d_in[3];
    const int*  edge_index = (const int*)d_in[4];
    const int*  bond_index = (const int*)d_in[5];
    const float* Wq1 = (const float*)d_in[6],  *Wk1 = (const float*)d_in[7],  *Wv1 = (const float*)d_in[8];
    const float* We0_1 = (const float*)d_in[9], *We1_1 = (const float*)d_in[10];
    const float* m1W1 = (const float*)d_in[11], *m1b1 = (const float*)d_in[12];
    const float* m1W2 = (const float*)d_in[13], *m1b2 = (const float*)d_in[14];
    const float* Wq2 = (const float*)d_in[15], *Wk2 = (const float*)d_in[16], *Wv2 = (const float*)d_in[17];
    const float* We0_2 = (const float*)d_in[18], *We1_2 = (const float*)d_in[19];
    const float* m2W1 = (const float*)d_in[20], *m2b1 = (const float*)d_in[21];
    const float* m2W2 = (const float*)d_in[22], *m2b2 = (const float*)d_in[23];
    const float* linW = (const float*)d_in[24], *linb = (const float*)d_in[25];
    const float* ff1W = (const float*)d_in[26], *ff1b = (const float*)d_in[27];
    const float* ff2W = (const float*)d_in[28], *ff2b = (const float*)d_in[29];
    float* out = (float*)d_out;                       // reference output dtype is float32

    // ---- workspace carve (fp32 unless noted) ----
    float* f = (float*)d_ws;
    float* qbuf  = f; f += (size_t)NODES * HID;
    float* kbuf  = f; f += (size_t)NODES * HID;
    float* vbuf  = f; f += (size_t)NODES * HID;
    float* cat   = f; f += (size_t)NODES * 512;   // [attn_out | x]; also reused as ff1 output
    float* tmp1  = f; f += (size_t)NODES * HID;
    float* h1    = f; f += (size_t)NODES * HID;
    float* h2    = f; f += (size_t)NODES * HID;
    float* hn    = f; f += (size_t)NODES * HID;
    float* denom = f; f += (size_t)NODES * HEADS;
    float* alphaE= f; f += (size_t)NEDGE * HEADS;
    bf16* e0buf = (bf16*)f; f += (size_t)NEDGE * HID / 2;
    bf16* e1buf = (bf16*)f; f += (size_t)NEDGE * HID / 2;

    dim3 blk(256);
    dim3 gN((NODES + 63) / 64, HID / 64);      // [10000 x 256] gemms
    dim3 gN2((NODES + 63) / 64, 512 / 64);     // [10000 x 512]
    dim3 gE((NEDGE + 63) / 64, HID / 64);      // [240000 x 256]

    // ================= phase 1: dist-graph attention =================
    gemm_kernel<float, float, EPI_NONE><<<gN, blk, 0, stream>>>(h, Wq1, nullptr, nullptr, qbuf, NODES, HID, HID);
    gemm_kernel<float, float, EPI_NONE><<<gN, blk, 0, stream>>>(h, Wk1, nullptr, nullptr, kbuf, NODES, HID, HID);
    gemm_kernel<float, float, EPI_NONE><<<gN, blk, 0, stream>>>(h, Wv1, nullptr, nullptr, vbuf, NODES, HID, HID);
    edge_ef_kernel<<<dim3(2000, 2), dim3(128), 0, stream>>>(pos, edge_type, edge_index, We0_1, We1_1, e0buf, e1buf);
    zero_kernel<<<dim3((NODES * HEADS + 255) / 256), blk, 0, stream>>>(denom, NODES * HEADS);
    fill_cat_kernel<<<dim3(NODES * 512 / 256), blk, 0, stream>>>(h, cat);
    alpha_kernel<<<dim3(NEDGE * HEADS / 256), blk, 0, stream>>>(edge_index, qbuf, kbuf, e0buf, alphaE, denom, NEDGE);
    msg_kernel<<<dim3(NEDGE), blk, 0, stream>>>(edge_index, vbuf, e1buf, alphaE, denom, cat, NEDGE);
    gemm_kernel<float, float, EPI_BIAS><<<gN, blk, 0, stream>>>(cat, m1W1, m1b1, nullptr, tmp1, NODES, HID, 512);
    ln_kernel<true, false><<<dim3(NODES), blk, 0, stream>>>(tmp1, nullptr, tmp1, 1e-5f);
    gemm_kernel<float, float, EPI_BIAS><<<gN, blk, 0, stream>>>(tmp1, m1W2, m1b2, nullptr, h1, NODES, HID, HID);

    // ================= phase 2: bond-graph attention =================
    gemm_kernel<float, float, EPI_NONE><<<gN, blk, 0, stream>>>(h1, Wq2, nullptr, nullptr, qbuf, NODES, HID, HID);
    gemm_kernel<float, float, EPI_NONE><<<gN, blk, 0, stream>>>(h1, Wk2, nullptr, nullptr, kbuf, NODES, HID, HID);
    gemm_kernel<float, float, EPI_NONE><<<gN, blk, 0, stream>>>(h1, Wv2, nullptr, nullptr, vbuf, NODES, HID, HID);
    gemm_kernel<float, bf16, EPI_TANH><<<gE, blk, 0, stream>>>(h_bond, We0_2, nullptr, nullptr, e0buf, NBOND, HID, HID);
    gemm_kernel<float, bf16, EPI_TANH><<<gE, blk, 0, stream>>>(h_bond, We1_2, nullptr, nullptr, e1buf, NBOND, HID, HID);
    zero_kernel<<<dim3((NODES * HEADS + 255) / 256), blk, 0, stream>>>(denom, NODES * HEADS);
    fill_cat_kernel<<<dim3(NODES * 512 / 256), blk, 0, stream>>>(h1, cat);
    alpha_kernel<<<dim3(NBOND * HEADS / 256), blk, 0, stream>>>(bond_index, qbuf, kbuf, e0buf, alphaE, denom, NBOND);
    msg_kernel<<<dim3(NBOND), blk, 0, stream>>>(bond_index, vbuf, e1buf, alphaE, denom, cat, NBOND);
    gemm_kernel<float, float, EPI_BIAS><<<gN, blk, 0, stream>>>(cat, m2W1, m2b1, nullptr, tmp1, NODES, HID, 512);
    ln_kernel<true, false><<<dim3(NODES), blk, 0, stream>>>(tmp1, nullptr, tmp1, 1e-5f);
    gemm_kernel<float, float, EPI_BIAS><<<gN, blk, 0, stream>>>(tmp1, m2W2, m2b2, nullptr, h2, NODES, HID, HID);

    // ================= phase 3: residual + LN + feed-forward =================
    gemm_kernel<float, float, EPI_BIAS><<<gN, blk, 0, stream>>>(h2, linW, linb, nullptr, tmp1, NODES, HID, HID);
    ln_kernel<false, true><<<dim3(NODES), blk, 0, stream>>>(tmp1, h, hn, 1e-6f);
    gemm_kernel<float, float, EPI_BIAS_SILU><<<gN2, blk, 0, stream>>>(hn, ff1W, ff1b, nullptr, cat, NODES, 512, HID);
    gemm_kernel<float, float, EPI_BIAS_ADD><<<gN, blk, 0, stream>>>(cat, ff2W, ff2b, hn, out, NODES, HID, 512);
}